// Round 4
// baseline (252.388 us; speedup 1.0000x reference)
//
#include <hip/hip_runtime.h>
#include <stdint.h>

#define JX 2048
#define JQ 128
#define DEN 256
#define NB 64

typedef __attribute__((ext_vector_type(4))) float f32x4;
typedef __attribute__((ext_vector_type(8))) short short8;
typedef _Float16 f16x8 __attribute__((ext_vector_type(8)));

typedef __attribute__((address_space(1))) const unsigned int as1_uint;
typedef __attribute__((address_space(3))) unsigned int as3_uint;

__device__ __forceinline__ unsigned short f2bf(float f) {
  union { float f; unsigned int u; } v; v.f = f;
  unsigned int r = v.u + 0x7FFFu + ((v.u >> 16) & 1u);
  return (unsigned short)(r >> 16);
}
__device__ __forceinline__ float bf2f(unsigned short b) {
  union { float f; unsigned int u; } v; v.u = ((unsigned int)b) << 16;
  return v.f;
}
__device__ __forceinline__ void gload_lds16(const void* src, void* dst) {
  __builtin_amdgcn_global_load_lds((as1_uint*)src, (as3_uint*)dst, 16, 0, 0);
}

// K0: u fp32 [n][128][256] -> u_hi,u_lo bf16 row-major + uT f16 [n][256][128]
__global__ __launch_bounds__(256) void k0_prep_u(const float* __restrict__ u,
    unsigned short* __restrict__ u_hi, unsigned short* __restrict__ u_lo,
    _Float16* __restrict__ uT16) {
  int n = blockIdx.y, dc = blockIdx.x, t = threadIdx.x;
  const float* un = u + (size_t)n * JQ * DEN;
  unsigned short* uhn = u_hi + (size_t)n * JQ * DEN;
  unsigned short* uln = u_lo + (size_t)n * JQ * DEN;
  __shared__ float lds[JQ * 65];
  for (int i = t; i < JQ * 64; i += 256) {
    int q = i >> 6, dl = i & 63;
    int idx = q * DEN + dc * 64 + dl;
    float f = un[idx];
    unsigned short hi = f2bf(f);
    uhn[idx] = hi;
    uln[idx] = f2bf(f - bf2f(hi));
    lds[q * 65 + dl] = f;
  }
  __syncthreads();
  _Float16* utn = uT16 + (size_t)n * DEN * JQ;
  for (int i = t; i < 64 * JQ; i += 256) {
    int dl = i >> 7, q = i & 127;
    utn[(size_t)(dc * 64 + dl) * JQ + q] = (_Float16)lds[q * 65 + dl];
  }
}

// K1: swapped-operand scheme. Per block (xb, n): 128 x-rows, 4 waves x 32 rows.
// QK: s^T = MFMA(A=u (hi/lo bf16), B=h (hi/lo bf16)); lane holds s[q][x=l15].
// Softmax over q: in-lane + shfl(16,32). p staged to per-wave pLds[x][q] (f16).
// PV: u_tilde^T = MFMA(A=uT f16 staged, B=p); C gives 4 consecutive d per lane ->
// direct f32x4 epilogue stores of quarters 1,2,3. Double-buffered staging.
__global__ __launch_bounds__(256, 2) void k1_attn(
    const float* __restrict__ h, const unsigned short* __restrict__ u_hi,
    const unsigned short* __restrict__ u_lo, const _Float16* __restrict__ uT16,
    float* __restrict__ out, float* __restrict__ mbuf) {
  __shared__ __align__(16) unsigned char UB[2][16384];
  __shared__ __align__(16) unsigned char PL[4][8192];

  const int n = blockIdx.y, xb = blockIdx.x;
  const int tid = threadIdx.x;
  const int wave = tid >> 6, lane = tid & 63;
  const int l15 = lane & 15, lq = lane >> 4;
  const int rowbase = xb * 128 + wave * 32;

  const char* uhB = (const char*)(u_hi + (size_t)n * JQ * DEN);
  const char* ulB = (const char*)(u_lo + (size_t)n * JQ * DEN);
  const char* uTB = (const char*)(uT16 + (size_t)n * DEN * JQ);

  const float* hr0 = h + (size_t)(n * JX + rowbase + l15) * DEN;
  const float* hr1 = hr0 + (size_t)16 * DEN;

  f32x4 acc[2][8];
#pragma unroll
  for (int t = 0; t < 2; ++t)
#pragma unroll
    for (int q = 0; q < 8; ++q) acc[t][q] = (f32x4)(0.f);

  // ---- QK: 8 chunks of 32 k-cols, double-buffered ----
  // chunk layout: hi [128 q][32 k]bf16 @0 (64B rows), lo @8192. Linear (no swizzle:
  // 16 rows x 4 blocks covers all banks uniformly).
  {
    // stage chunk 0, prefetch h chunk 0
#pragma unroll
    for (int rr = 0; rr < 2; ++rr) {
      int L = rr * 4096 + tid * 16;
      int row = L >> 6, cb = (L >> 4) & 3;
      gload_lds16(uhB + (size_t)row * 512 + 0 * 64 + cb * 16, &UB[0][L]);
      gload_lds16(ulB + (size_t)row * 512 + 0 * 64 + cb * 16, &UB[0][8192 + L]);
    }
  }
  f32x4 hnx[2][2];
  hnx[0][0] = *(const f32x4*)(hr0 + lq * 8);
  hnx[0][1] = *(const f32x4*)(hr0 + lq * 8 + 4);
  hnx[1][0] = *(const f32x4*)(hr1 + lq * 8);
  hnx[1][1] = *(const f32x4*)(hr1 + lq * 8 + 4);
  __syncthreads();

#pragma unroll
  for (int c = 0; c < 8; ++c) {
    const int b = c & 1;
    if (c < 7) {  // stage next chunk into other buffer
      const int nb2 = (c + 1) & 1;
#pragma unroll
      for (int rr = 0; rr < 2; ++rr) {
        int L = rr * 4096 + tid * 16;
        int row = L >> 6, cb = (L >> 4) & 3;
        gload_lds16(uhB + (size_t)row * 512 + (c + 1) * 64 + cb * 16, &UB[nb2][L]);
        gload_lds16(ulB + (size_t)row * 512 + (c + 1) * 64 + cb * 16, &UB[nb2][8192 + L]);
      }
    }
    f32x4 hc[2][2];
#pragma unroll
    for (int t = 0; t < 2; ++t) { hc[t][0] = hnx[t][0]; hc[t][1] = hnx[t][1]; }
    if (c < 7) {
      hnx[0][0] = *(const f32x4*)(hr0 + (c + 1) * 32 + lq * 8);
      hnx[0][1] = *(const f32x4*)(hr0 + (c + 1) * 32 + lq * 8 + 4);
      hnx[1][0] = *(const f32x4*)(hr1 + (c + 1) * 32 + lq * 8);
      hnx[1][1] = *(const f32x4*)(hr1 + (c + 1) * 32 + lq * 8 + 4);
    }
    short8 bhi[2], blo[2];
#pragma unroll
    for (int t = 0; t < 2; ++t)
#pragma unroll
      for (int j = 0; j < 8; ++j) {
        float f = (j < 4) ? hc[t][0][j] : hc[t][1][j - 4];
        unsigned short hb = f2bf(f);
        bhi[t][j] = (short)hb;
        blo[t][j] = (short)f2bf(f - bf2f(hb));
      }
#pragma unroll
    for (int qt = 0; qt < 8; ++qt) {
      short8 uhf = *(const short8*)(&UB[b][(qt * 16 + l15) * 64 + lq * 16]);
      short8 ulf = *(const short8*)(&UB[b][8192 + (qt * 16 + l15) * 64 + lq * 16]);
      acc[0][qt] = __builtin_amdgcn_mfma_f32_16x16x32_bf16(ulf, bhi[0], acc[0][qt], 0, 0, 0);
      acc[0][qt] = __builtin_amdgcn_mfma_f32_16x16x32_bf16(uhf, blo[0], acc[0][qt], 0, 0, 0);
      acc[0][qt] = __builtin_amdgcn_mfma_f32_16x16x32_bf16(uhf, bhi[0], acc[0][qt], 0, 0, 0);
      acc[1][qt] = __builtin_amdgcn_mfma_f32_16x16x32_bf16(ulf, bhi[1], acc[1][qt], 0, 0, 0);
      acc[1][qt] = __builtin_amdgcn_mfma_f32_16x16x32_bf16(uhf, blo[1], acc[1][qt], 0, 0, 0);
      acc[1][qt] = __builtin_amdgcn_mfma_f32_16x16x32_bf16(uhf, bhi[1], acc[1][qt], 0, 0, 0);
    }
    __syncthreads();
  }

  // ---- pre-stage uT chunks 0,1 (latency hidden under softmax) ----
#pragma unroll
  for (int pc = 0; pc < 2; ++pc) {
#pragma unroll
    for (int rr = 0; rr < 4; ++rr) {
      int L = rr * 4096 + tid * 16;
      int row = L >> 8;
      int cb = (tid & 15) ^ (row & 7);
      gload_lds16(uTB + (size_t)(pc * 64 + row) * 256 + cb * 16, &UB[pc][L]);
    }
  }

  // ---- softmax over q (lane-local x = l15) ----
  float rinv[2];
#pragma unroll
  for (int t = 0; t < 2; ++t) {
    float mv = acc[t][0][0];
#pragma unroll
    for (int qt = 0; qt < 8; ++qt)
#pragma unroll
      for (int r = 0; r < 4; ++r) mv = fmaxf(mv, acc[t][qt][r]);
    mv = fmaxf(mv, __shfl_xor(mv, 16));
    mv = fmaxf(mv, __shfl_xor(mv, 32));
    float s = 0.f;
#pragma unroll
    for (int qt = 0; qt < 8; ++qt)
#pragma unroll
      for (int r = 0; r < 4; ++r) {
        float p = __expf(acc[t][qt][r] - mv);
        acc[t][qt][r] = p;
        s += p;
      }
    s += __shfl_xor(s, 16);
    s += __shfl_xor(s, 32);
    rinv[t] = 1.f / s;
    if (lq == 0) mbuf[n * JX + rowbase + t * 16 + l15] = mv;
  }

  // ---- p -> per-wave pLds[x=32][q=128] f16, 256B rows, 16B-block XOR swizzle ----
  char* pw = (char*)PL[wave];
  const int swz = (l15 & 7) << 4;
#pragma unroll
  for (int t = 0; t < 2; ++t)
#pragma unroll
    for (int qt = 0; qt < 8; ++qt) {
      union { _Float16 hx[4]; uint2 u; } pk;
#pragma unroll
      for (int r = 0; r < 4; ++r) pk.hx[r] = (_Float16)acc[t][qt][r];
      *(uint2*)(pw + (t * 16 + l15) * 256 + ((32 * qt + 8 * lq) ^ swz)) = pk.u;
    }
  __syncthreads();  // drains uT0,uT1 staging; pLds is wave-private (no cross-wave reads)

  // ---- PV + direct epilogue: 4 chunks of 64 d-cols ----
#pragma unroll
  for (int c = 0; c < 4; ++c) {
    const int b = c & 1;
    f32x4 vacc[2][4];
#pragma unroll
    for (int t = 0; t < 2; ++t)
#pragma unroll
      for (int dt = 0; dt < 4; ++dt) vacc[t][dt] = (f32x4)(0.f);
#pragma unroll
    for (int ks = 0; ks < 4; ++ks) {
      f16x8 pf[2];
#pragma unroll
      for (int t = 0; t < 2; ++t)
        pf[t] = *(const f16x8*)(pw + (t * 16 + l15) * 256 + ((64 * ks + 16 * lq) ^ swz));
#pragma unroll
      for (int dt = 0; dt < 4; ++dt) {
        f16x8 af = *(const f16x8*)(&UB[b][(dt * 16 + l15) * 256 + ((64 * ks + 16 * lq) ^ swz)]);
        vacc[0][dt] = __builtin_amdgcn_mfma_f32_16x16x32_f16(af, pf[0], vacc[0][dt], 0, 0, 0);
        vacc[1][dt] = __builtin_amdgcn_mfma_f32_16x16x32_f16(af, pf[1], vacc[1][dt], 0, 0, 0);
      }
    }
    __syncthreads();  // all waves done reading UB[b]
    if (c + 2 < 4) {  // stage chunk c+2 into the just-freed buffer
#pragma unroll
      for (int rr = 0; rr < 4; ++rr) {
        int L = rr * 4096 + tid * 16;
        int row = L >> 8;
        int cb = (tid & 15) ^ (row & 7);
        gload_lds16(uTB + (size_t)((c + 2) * 64 + row) * 256 + cb * 16, &UB[b][L]);
      }
    }
    // epilogue: lane holds d = c*64 + dt*16 + lq*4 + r for row x = t*16+l15
#pragma unroll
    for (int t = 0; t < 2; ++t)
#pragma unroll
      for (int dt = 0; dt < 4; ++dt) {
        f32x4 ut = vacc[t][dt] * rinv[t];
        int colbase = c * 64 + dt * 16 + lq * 4;
        size_t xg = (size_t)(n * JX + rowbase + t * 16 + l15);
        f32x4 hv = *(const f32x4*)(h + xg * DEN + colbase);
        float* op = out + xg * 1024 + colbase;
        *(f32x4*)op = hv;
        *(f32x4*)(op + 256) = ut;
        *(f32x4*)(op + 512) = hv * ut;
      }
  }
}

// K2a: per n: b = softmax over JX of rowmax m
__global__ __launch_bounds__(256) void k2a_bsoftmax(const float* __restrict__ mbuf,
                                                    float* __restrict__ bbuf) {
  int n = blockIdx.x, t = threadIdx.x;
  const float* mn = mbuf + (size_t)n * JX;
  float vals[8];
  float lm = -3.4e38f;
#pragma unroll
  for (int i = 0; i < 8; ++i) { vals[i] = mn[t + i * 256]; lm = fmaxf(lm, vals[i]); }
  for (int sh = 1; sh <= 32; sh <<= 1) lm = fmaxf(lm, __shfl_xor(lm, sh));
  __shared__ float red[4], red2[4];
  int wave = t >> 6;
  if ((t & 63) == 0) red[wave] = lm;
  __syncthreads();
  lm = fmaxf(fmaxf(red[0], red[1]), fmaxf(red[2], red[3]));
  float ls = 0.f;
#pragma unroll
  for (int i = 0; i < 8; ++i) { vals[i] = __expf(vals[i] - lm); ls += vals[i]; }
  for (int sh = 1; sh <= 32; sh <<= 1) ls += __shfl_xor(ls, sh);
  if ((t & 63) == 0) red2[wave] = ls;
  __syncthreads();
  ls = red2[0] + red2[1] + red2[2] + red2[3];
  float inv = 1.f / ls;
  float* bn = bbuf + (size_t)n * JX;
#pragma unroll
  for (int i = 0; i < 8; ++i) bn[t + i * 256] = vals[i] * inv;
}

// K2b: partial h_tilde over x-chunks (deterministic, no atomics)
__global__ __launch_bounds__(256) void k2b_htilde_partial(const float* __restrict__ h,
    const float* __restrict__ bbuf, float* __restrict__ part) {
  int n = blockIdx.y, cidx = blockIdx.x, t = threadIdx.x;
  const float* hn = h + ((size_t)n * JX + cidx * 128) * DEN;
  const float* bn = bbuf + (size_t)n * JX + cidx * 128;
  float accv = 0.f;
  for (int x = 0; x < 128; ++x) accv += bn[x] * hn[(size_t)x * DEN + t];
  part[((size_t)n * 16 + cidx) * DEN + t] = accv;
}

// K3: reduce partials, write quarter 4 (h*h_tilde). grid (64, NB), 32 rows/block.
__global__ __launch_bounds__(256) void k3_quarter4(const float* __restrict__ h,
    const float* __restrict__ part, float* __restrict__ out) {
  int n = blockIdx.y, xc = blockIdx.x, t = threadIdx.x;
  __shared__ float ht[DEN];
  float s = 0.f;
#pragma unroll
  for (int c = 0; c < 16; ++c) s += part[((size_t)n * 16 + c) * DEN + t];
  ht[t] = s;
  __syncthreads();
  int wave = t >> 6, c4 = t & 63;
  f32x4 htv = *(const f32x4*)(ht + c4 * 4);
#pragma unroll
  for (int i = 0; i < 8; ++i) {
    int row = xc * 32 + i * 4 + wave;
    f32x4 hv = *(const f32x4*)(h + (size_t)(n * JX + row) * DEN + c4 * 4);
    *(f32x4*)(out + (size_t)(n * JX + row) * 1024 + 768 + c4 * 4) = hv * htv;
  }
}

extern "C" void kernel_launch(void* const* d_in, const int* in_sizes, int n_in,
                              void* d_out, int out_size, void* d_ws, size_t ws_size,
                              hipStream_t stream) {
  const float* h = (const float*)d_in[0];
  const float* u = (const float*)d_in[1];
  float* out = (float*)d_out;
  char* ws = (char*)d_ws;

  size_t off = 0;
  unsigned short* u_hi = (unsigned short*)(ws + off); off += (size_t)NB * JQ * DEN * 2;
  unsigned short* u_lo = (unsigned short*)(ws + off); off += (size_t)NB * JQ * DEN * 2;
  _Float16* uT16 = (_Float16*)(ws + off); off += (size_t)NB * DEN * JQ * 2;
  float* mbuf = (float*)(ws + off); off += (size_t)NB * JX * 4;
  float* bbuf = (float*)(ws + off); off += (size_t)NB * JX * 4;
  float* part = (float*)(ws + off); off += (size_t)NB * 16 * DEN * 4;

  hipLaunchKernelGGL(k0_prep_u, dim3(4, NB), dim3(256), 0, stream, u, u_hi, u_lo, uT16);
  hipLaunchKernelGGL(k1_attn, dim3(JX / 128, NB), dim3(256), 0, stream,
                     h, u_hi, u_lo, uT16, out, mbuf);
  hipLaunchKernelGGL(k2a_bsoftmax, dim3(NB), dim3(256), 0, stream, mbuf, bbuf);
  hipLaunchKernelGGL(k2b_htilde_partial, dim3(16, NB), dim3(256), 0, stream, h, bbuf, part);
  hipLaunchKernelGGL(k3_quarter4, dim3(64, NB), dim3(256), 0, stream, h, part, out);
}